// Round 4
// baseline (15622.751 us; speedup 1.0000x reference)
//
#include <hip/hip_runtime.h>
#include <stdint.h>

// Problem constants
#define LNUM 4
#define BB   32
#define TT   2048
#define DD   512
#define HH   512
#define BT   (BB*TT)          // 65536
#define EPSF 1e-5f

typedef __attribute__((ext_vector_type(8))) _Float16 h8;   // 4 VGPR MFMA A/B frag
typedef __attribute__((ext_vector_type(4))) float    f4;   // MFMA C/D frag

// ---------------- workspace layout (bytes) ----------------
// wblob: 9 weight mats in MFMA B-frag blob order (4.5 MiB)
// lni2 : LN(zi) in k_rnn lane-layout  [lc=l*2+ch][t][np16][lane64][8] f16 (256 MiB)
// h3   : h of layer 3, [b][t][j] f16 (64 MiB)
// pz   : partial-z exchange, [lc][parity][kh][chain16][n512] u32 (1 MiB)
#define WS_WBLOB  ((size_t)0)
#define WS_LNI    (WS_WBLOB + (size_t)9*16*32*64*8*2)
#define WS_H3     (WS_LNI + (size_t)8*TT*8192*2)
#define WS_PZ     (WS_H3  + (size_t)BT*HH*2)
#define WS_END    (WS_PZ  + (size_t)8*2*2*8192*4)

// ---------------- prep: weights -> f16 fragment blobs ----------------
// blob elem index: (((wi*16+kt)*32 + nt)*64 + lane)*8 + e  == W[n][k],
//   n = nt*16 + (lane&15), k = kt*32 + (lane>>4)*8 + e   (MFMA B-frag layout)
__global__ void k_prep_w(const float* __restrict__ Wih, const float* __restrict__ Whh,
                         const float* __restrict__ Who, _Float16* __restrict__ wblob) {
  int wi = blockIdx.x >> 4;
  int kt = blockIdx.x & 15;
  const float* S = (wi < 4) ? (Wih + (size_t)wi*HH*DD)
                 : (wi < 8) ? (Whh + (size_t)(wi-4)*HH*HH)
                            :  Who;
  for (int it = 0; it < 8; ++it) {
    int flat = it*256 + threadIdx.x;          // 0..2047 = nt*64+lane
    int lane = flat & 63;
    int n  = (flat >> 6)*16 + (lane & 15);
    int k0 = kt*32 + (lane >> 4)*8;
    const float* s = S + (size_t)n*512 + k0;
    h8 h;
    #pragma unroll
    for (int e = 0; e < 8; ++e) h[e] = (_Float16)s[e];
    *(h8*)(wblob + (size_t)(wi*16+kt)*16384 + (size_t)flat*8) = h;
  }
}

// ---------------- phase A: zi GEMM + fused LayerNorm -> lni2 ----------------
__launch_bounds__(256,1)
__global__ void k_gemm_lni(const float* __restrict__ x,
                           const _Float16* __restrict__ wblob,
                           const float* __restrict__ b_ih,
                           const float* __restrict__ g_ih,
                           const float* __restrict__ be_ih,
                           _Float16* __restrict__ lni) {
  __shared__ __align__(16) _Float16 Bst[16384];   // 32 KB frag-order W chunk
  __shared__ __align__(16) char     Ast[64*80];   // 64 rows x 32 f16, 80B padded stride
  __shared__ float stats[4][4][16][2];
  int tid = threadIdx.x, lane = tid & 63, w = tid >> 6;
  int ln15 = lane & 15;
  int l   = blockIdx.x >> 10;
  int rb0 = (blockIdx.x & 1023) * 64;

  float breg[8], greg[8], bereg[8];
  #pragma unroll
  for (int i = 0; i < 8; ++i) {
    int j = (w*8+i)*16 + ln15;
    breg[i]  = b_ih [l*512 + j];
    greg[i]  = g_ih [l*512 + j];
    bereg[i] = be_ih[l*512 + j];
  }
  f4 acc[4][8];
  #pragma unroll
  for (int mt = 0; mt < 4; ++mt)
    #pragma unroll
    for (int i = 0; i < 8; ++i) acc[mt][i] = (f4){0.f,0.f,0.f,0.f};

  for (int kt = 0; kt < 16; ++kt) {
    const _Float16* bsrc = wblob + (size_t)(l*16 + kt)*16384;
    #pragma unroll
    for (int it = 0; it < 8; ++it) {
      int off = it*2048 + tid*8;
      *(uint4*)&Bst[off] = *(const uint4*)&bsrc[off];
    }
    { int row = tid >> 2, slot = tid & 3;
      const float* asrc = x + (size_t)(rb0+row)*512 + kt*32 + slot*8;
      float4 fa = *(const float4*)asrc;
      float4 fb = *(const float4*)(asrc + 4);
      h8 hv;
      hv[0]=(_Float16)fa.x; hv[1]=(_Float16)fa.y; hv[2]=(_Float16)fa.z; hv[3]=(_Float16)fa.w;
      hv[4]=(_Float16)fb.x; hv[5]=(_Float16)fb.y; hv[6]=(_Float16)fb.z; hv[7]=(_Float16)fb.w;
      *(h8*)&Ast[row*80 + slot*16] = hv; }
    __syncthreads();
    h8 af[4];
    #pragma unroll
    for (int mt = 0; mt < 4; ++mt)
      af[mt] = *(const h8*)&Ast[(mt*16 + ln15)*80 + (lane>>4)*16];
    #pragma unroll
    for (int i = 0; i < 8; ++i) {
      h8 bf = *(const h8*)&Bst[((w*8+i)*64 + lane)*8];
      #pragma unroll
      for (int mt = 0; mt < 4; ++mt)
        acc[mt][i] = __builtin_amdgcn_mfma_f32_16x16x32_f16(af[mt], bf, acc[mt][i], 0,0,0);
    }
    __syncthreads();
  }
  // epilogue: bias + LN stats (row = rb0 + mt*16 + (lane>>4)*4 + r, col j)
  float ps[4][4], pq[4][4];
  #pragma unroll
  for (int mt = 0; mt < 4; ++mt)
    #pragma unroll
    for (int r = 0; r < 4; ++r) { ps[mt][r] = 0.f; pq[mt][r] = 0.f; }
  #pragma unroll
  for (int mt = 0; mt < 4; ++mt)
    #pragma unroll
    for (int i = 0; i < 8; ++i)
      #pragma unroll
      for (int r = 0; r < 4; ++r) {
        float v = acc[mt][i][r] + breg[i];
        acc[mt][i][r] = v;
        ps[mt][r] += v; pq[mt][r] += v*v;
      }
  #pragma unroll
  for (int m = 1; m < 16; m <<= 1)
    #pragma unroll
    for (int mt = 0; mt < 4; ++mt)
      #pragma unroll
      for (int r = 0; r < 4; ++r) {
        ps[mt][r] += __shfl_xor(ps[mt][r], m);
        pq[mt][r] += __shfl_xor(pq[mt][r], m);
      }
  if (ln15 == 0) {
    int g = lane >> 4;
    #pragma unroll
    for (int mt = 0; mt < 4; ++mt)
      #pragma unroll
      for (int r = 0; r < 4; ++r) {
        stats[w][mt][g*4+r][0] = ps[mt][r];
        stats[w][mt][g*4+r][1] = pq[mt][r];
      }
  }
  __syncthreads();
  #pragma unroll
  for (int mt = 0; mt < 4; ++mt)
    #pragma unroll
    for (int r = 0; r < 4; ++r) {
      int rowm = (lane>>4)*4 + r;
      float s = 0.f, q = 0.f;
      #pragma unroll
      for (int ww = 0; ww < 4; ++ww) { s += stats[ww][mt][rowm][0]; q += stats[ww][mt][rowm][1]; }
      float mu = s * (1.f/512.f);
      float rs = rsqrtf(q*(1.f/512.f) - mu*mu + EPSF);
      int rglob = rb0 + mt*16 + rowm;
      int b = rglob >> 11, t = rglob & 2047;
      int ch = b >> 4, c = b & 15;
      // lane-layout store: [lc][t][np=j>>5][lane2=(c>>2)*16+(j&15)][slot=((j>>4)&1)*4+(c&3)]
      _Float16* dst = lni + ((size_t)(l*2 + ch)*2048 + t)*8192;
      #pragma unroll
      for (int i = 0; i < 8; ++i) {
        int j = (w*8+i)*16 + ln15;
        size_t a2 = ((size_t)(j>>5)*64 + (c>>2)*16 + (j&15))*8 + ((j>>4)&1)*4 + (c&3);
        dst[a2] = (_Float16)((acc[mt][i][r] - mu)*rs*greg[i] + bereg[i]);
      }
    }
}

// ---------------- recurrence: 16 blocks, K-half x chain-half ----------------
// bid: l=bid>>2, ch=(bid>>1)&1 (chains b=ch*16+c), kh=bid&1 (K-half); partner=bid^1
// Each block: W_hh[l][all 512 n][own 256 k] in regs (128 VGPR/lane), computes
// partial z for its 16 chains; one tagged relaxed-atomic exchange per step.
// Hang-proof: cumulative poll budget -> kernel always terminates.
__launch_bounds__(512,2)
__global__ void k_rnn(const _Float16* __restrict__ wblob,
                      const _Float16* __restrict__ lni2,
                      const float* __restrict__ b_hh,
                      const float* __restrict__ g_hh,
                      const float* __restrict__ be_hh,
                      _Float16* __restrict__ h3,
                      float* __restrict__ hfin,
                      unsigned int* __restrict__ pz) {
  __shared__ __align__(16) _Float16 hA[16*256];   // [chain][own-k], XOR-swizzled, 8 KB
  __shared__ float stats[8][16][2];
  __shared__ float bstats[16][2];

  const int tid = threadIdx.x, lane = tid & 63, w = tid >> 6;
  const int bid = blockIdx.x;
  const int l = bid >> 2, ch = (bid >> 1) & 1, kh = bid & 1;
  const int lc = l*2 + ch;
  const int g = lane >> 4, ln15 = lane & 15;
  const bool ownhalf = ((w >> 2) == kh);

  // W_hh own K-half -> registers: wf[q][i] = frag(kt=kh*8+q, nt=w*4+i)
  h8 wf[8][4];
  #pragma unroll
  for (int q = 0; q < 8; ++q) {
    int ktg = kh*8 + q;
    #pragma unroll
    for (int i = 0; i < 4; ++i) {
      int nt = w*4 + i;
      wf[q][i] = *(const h8*)(wblob +
        ((size_t)((4+l)*16 + ktg)*32 + nt)*512 + (size_t)lane*8);
    }
  }
  float bh[4], gh[4], beh[4];
  #pragma unroll
  for (int i = 0; i < 4; ++i) {
    int j = (w*4+i)*16 + ln15;
    bh[i] = b_hh[l*512 + j]; gh[i] = g_hh[l*512 + j]; beh[i] = be_hh[l*512 + j];
  }
  // h0 = 0 (8 KB = 512 threads x 16B)
  *(uint4*)((char*)hA + tid*16) = make_uint4(0,0,0,0);

  // LNi[t=0] per-lane prefetch (each lane's 2x16B are exactly its finish data)
  uint4 c0, c1;
  {
    const uint4* s = (const uint4*)(lni2 + (size_t)lc*2048*8192);
    c0 = s[(w*2+0)*64 + lane];
    c1 = s[(w*2+1)*64 + lane];
  }
  unsigned int* pzbase = pz + (size_t)lc*2*2*8192;
  int pollbudget = 1 << 22;   // cumulative across all steps: hang-proof
  __syncthreads();

  #pragma unroll 1
  for (int t = 0; t < TT; ++t) {
    // prefetch LNi[t+1]
    uint4 p0 = make_uint4(0,0,0,0), p1 = p0;
    if (t+1 < TT) {
      const uint4* s = (const uint4*)(lni2 + ((size_t)lc*2048 + t + 1)*8192);
      p0 = s[(w*2+0)*64 + lane];
      p1 = s[(w*2+1)*64 + lane];
    }
    // partial z = W_half . h_half   (A rows = chains, cols j = nt*16+ln15)
    f4 acc[4];
    #pragma unroll
    for (int i = 0; i < 4; ++i) acc[i] = (f4){0.f,0.f,0.f,0.f};
    #pragma unroll
    for (int q = 0; q < 8; ++q) {
      int a_off = (ln15*512 + q*64 + g*16) ^ ((ln15 & 7) << 4);  // bytes
      h8 a = *(const h8*)((const char*)hA + a_off);
      #pragma unroll
      for (int i = 0; i < 4; ++i)
        acc[i] = __builtin_amdgcn_mfma_f32_16x16x32_f16(a, wf[q][i], acc[i], 0,0,0);
    }
    const unsigned tg = (unsigned)((t+1) & 3);
    unsigned int* wp = pzbase + ((size_t)(t & 1)*2 + kh)*8192;
    unsigned int* rp = pzbase + ((size_t)(t & 1)*2 + (kh ^ 1))*8192;
    // publish own partials: f32 with tag in 2 LSBs of mantissa (relaxed, no fences)
    #pragma unroll
    for (int i = 0; i < 4; ++i)
      #pragma unroll
      for (int r = 0; r < 4; ++r) {
        int off = (g*4+r)*512 + (w*4+i)*16 + ln15;
        unsigned u = (__float_as_uint(acc[i][r]) & ~3u) | tg;
        __hip_atomic_store(wp + off, u, __ATOMIC_RELAXED, __HIP_MEMORY_SCOPE_AGENT);
      }
    __atomic_signal_fence(__ATOMIC_SEQ_CST);  // compiler: don't sink stores past poll
    // poll partner partials (pipelined first pass, then retry stale words)
    unsigned vv[16];
    #pragma unroll
    for (int q16 = 0; q16 < 16; ++q16) {
      int i = q16 >> 2, r = q16 & 3;
      int off = (g*4+r)*512 + (w*4+i)*16 + ln15;
      vv[q16] = __hip_atomic_load(rp + off, __ATOMIC_RELAXED, __HIP_MEMORY_SCOPE_AGENT);
    }
    while (pollbudget > 0) {
      bool ok = true;
      #pragma unroll
      for (int q16 = 0; q16 < 16; ++q16) {
        if ((vv[q16] & 3u) != tg) {
          ok = false;
          int i = q16 >> 2, r = q16 & 3;
          int off = (g*4+r)*512 + (w*4+i)*16 + ln15;
          vv[q16] = __hip_atomic_load(rp + off, __ATOMIC_RELAXED, __HIP_MEMORY_SCOPE_AGENT);
        }
      }
      if (ok) break;
      --pollbudget;
    }
    // full z + bias; LN stats over all 512 j (8 waves x 64 j each)
    float z[4][4];
    float ps[4] = {0,0,0,0}, pq[4] = {0,0,0,0};
    #pragma unroll
    for (int i = 0; i < 4; ++i)
      #pragma unroll
      for (int r = 0; r < 4; ++r) {
        float v = acc[i][r] + __uint_as_float(vv[i*4+r]) + bh[i];
        z[i][r] = v; ps[r] += v; pq[r] += v*v;
      }
    #pragma unroll
    for (int m = 1; m < 16; m <<= 1)
      #pragma unroll
      for (int r = 0; r < 4; ++r) { ps[r] += __shfl_xor(ps[r], m); pq[r] += __shfl_xor(pq[r], m); }
    if (ln15 == 0)
      #pragma unroll
      for (int r = 0; r < 4; ++r) { stats[w][g*4+r][0] = ps[r]; stats[w][g*4+r][1] = pq[r]; }
    __syncthreads();
    if (tid < 32) {
      int c = tid >> 1, sel = tid & 1;
      float s = 0.f;
      #pragma unroll
      for (int ww = 0; ww < 8; ++ww) s += stats[ww][c][sel];
      bstats[c][sel] = s;
    }
    __syncthreads();
    // finish: LN + LNi + tanh; write own-half h to hA, l3 h3, final h
    #pragma unroll
    for (int r = 0; r < 4; ++r) {
      int c = g*4 + r;
      float mu = bstats[c][0] * (1.f/512.f);
      float rs = rsqrtf(bstats[c][1]*(1.f/512.f) - mu*mu + EPSF);
      #pragma unroll
      for (int i = 0; i < 4; ++i) {
        int j = (w*4+i)*16 + ln15;
        h8 lc0 = *(h8*)&c0, lc1 = *(h8*)&c1;
        float lniv = (float)((i < 2) ? lc0[(i&1)*4 + r] : lc1[(i&1)*4 + r]);
        float pre = (z[i][r] - mu)*rs*gh[i] + beh[i] + lniv;
        float e = __expf(2.f*pre);
        float hv = 1.f - 2.f*__builtin_amdgcn_rcpf(e + 1.f);
        if (ownhalf) {
          int kl = j - kh*256;
          int ha_off = (c*512 + kl*2) ^ ((c & 7) << 4);
          *(_Float16*)((char*)hA + ha_off) = (_Float16)hv;
        }
        if (l == 3 && kh == 0)
          h3[((size_t)(ch*16 + c)*2048 + t)*512 + j] = (_Float16)hv;
        if (t == TT-1 && kh == 0)
          hfin[((size_t)l*32 + ch*16 + c)*512 + j] = hv;
      }
    }
    __syncthreads();
    c0 = p0; c1 = p1;
  }
}

// ---------------- phase C: out = h3*W_ho^T + b_ho + x ----------------
__launch_bounds__(256,1)
__global__ void k_gemm_out(const _Float16* __restrict__ h3,
                           const _Float16* __restrict__ wblob,
                           const float* __restrict__ b_ho,
                           const float* __restrict__ x,
                           float* __restrict__ out) {
  __shared__ __align__(16) _Float16 Bst[16384];
  __shared__ __align__(16) char     Ast[64*80];
  int tid = threadIdx.x, lane = tid & 63, w = tid >> 6;
  int rb0 = blockIdx.x * 64;
  float breg[8];
  #pragma unroll
  for (int i = 0; i < 8; ++i) breg[i] = b_ho[(w*8+i)*16 + (lane & 15)];
  f4 acc[4][8];
  #pragma unroll
  for (int mt = 0; mt < 4; ++mt)
    #pragma unroll
    for (int i = 0; i < 8; ++i) acc[mt][i] = (f4){0.f,0.f,0.f,0.f};
  for (int kt = 0; kt < 16; ++kt) {
    const _Float16* bsrc = wblob + (size_t)(128 + kt)*16384;  // wi=8 (W_ho)
    #pragma unroll
    for (int it = 0; it < 8; ++it) {
      int off = it*2048 + tid*8;
      *(uint4*)&Bst[off] = *(const uint4*)&bsrc[off];
    }
    { int row = tid >> 2, slot = tid & 3;
      const _Float16* asrc = h3 + (size_t)(rb0+row)*512 + kt*32 + slot*8;
      *(uint4*)&Ast[row*80 + slot*16] = *(const uint4*)asrc; }
    __syncthreads();
    h8 af[4];
    #pragma unroll
    for (int mt = 0; mt < 4; ++mt)
      af[mt] = *(const h8*)&Ast[(mt*16 + (lane&15))*80 + (lane>>4)*16];
    #pragma unroll
    for (int i = 0; i < 8; ++i) {
      h8 bf = *(const h8*)&Bst[((w*8+i)*64 + lane)*8];
      #pragma unroll
      for (int mt = 0; mt < 4; ++mt)
        acc[mt][i] = __builtin_amdgcn_mfma_f32_16x16x32_f16(af[mt], bf, acc[mt][i], 0,0,0);
    }
    __syncthreads();
  }
  #pragma unroll
  for (int mt = 0; mt < 4; ++mt)
    #pragma unroll
    for (int r = 0; r < 4; ++r) {
      int rglob = rb0 + mt*16 + (lane>>4)*4 + r;
      #pragma unroll
      for (int i = 0; i < 8; ++i) {
        int j = (w*8+i)*16 + (lane & 15);
        out[(size_t)rglob*512 + j] = acc[mt][i][r] + breg[i] + x[(size_t)rglob*512 + j];
      }
    }
}

extern "C" void kernel_launch(void* const* d_in, const int* in_sizes, int n_in,
                              void* d_out, int out_size, void* d_ws, size_t ws_size,
                              hipStream_t stream) {
  const float* x    = (const float*)d_in[0];
  const float* Wih  = (const float*)d_in[1];
  const float* bih  = (const float*)d_in[2];
  const float* gih  = (const float*)d_in[3];
  const float* beih = (const float*)d_in[4];
  const float* Whh  = (const float*)d_in[5];
  const float* bhh  = (const float*)d_in[6];
  const float* ghh  = (const float*)d_in[7];
  const float* behh = (const float*)d_in[8];
  const float* Who  = (const float*)d_in[9];
  const float* bho  = (const float*)d_in[10];
  if (ws_size < WS_END) return;   // need ~341 MiB scratch
  char* ws = (char*)d_ws;
  _Float16* wblob = (_Float16*)(ws + WS_WBLOB);
  _Float16* lni   = (_Float16*)(ws + WS_LNI);
  _Float16* h3    = (_Float16*)(ws + WS_H3);
  unsigned int* pz = (unsigned int*)(ws + WS_PZ);
  float* outp = (float*)d_out;

  hipMemsetAsync(pz, 0, (size_t)8*2*2*8192*4, stream);   // init tag 0 != first tags 1,2
  k_prep_w  <<<144,  256, 0, stream>>>(Wih, Whh, Who, wblob);
  k_gemm_lni<<<4096, 256, 0, stream>>>(x, wblob, bih, gih, beih, lni);
  k_rnn     <<<16,   512, 0, stream>>>(wblob, lni, bhh, ghh, behh, h3,
                                       outp + (size_t)BT*DD, pz);
  k_gemm_out<<<1024, 256, 0, stream>>>(h3, wblob, bho, x, outp);
}

// Round 6
// 13413.391 us; speedup vs baseline: 1.1647x; 1.1647x over previous
//
#include <hip/hip_runtime.h>
#include <stdint.h>

// Problem constants
#define LNUM 4
#define BB   32
#define TT   2048
#define DD   512
#define HH   512
#define BT   (BB*TT)          // 65536
#define EPSF 1e-5f

typedef __attribute__((ext_vector_type(8))) _Float16 h8;   // 4 VGPR MFMA A/B frag
typedef __attribute__((ext_vector_type(4))) float    f4;   // MFMA C/D frag

// ---------------- workspace layout (bytes) ----------------
// wblob: 9 weight mats in MFMA B-frag blob order (4.5 MiB)
// lni2 : LN(zi) in k_rnn lane-layout  [lc=l*2+ch][t][np16][lane64][8] f16 (256 MiB)
// h3   : h of layer 3, [b][t][j] f16 (64 MiB)
// pz   : partial-z exchange, [lc][parity][kh][q8][tid512] u64 (1 MiB)
#define WS_WBLOB  ((size_t)0)
#define WS_LNI    (WS_WBLOB + (size_t)9*16*32*64*8*2)
#define WS_H3     (WS_LNI + (size_t)8*TT*8192*2)
#define WS_PZ     (WS_H3  + (size_t)BT*HH*2)
#define WS_END    (WS_PZ  + (size_t)8*2*2*8*512*8)

// ---------------- prep: weights -> f16 fragment blobs ----------------
// blob elem index: (((wi*16+kt)*32 + nt)*64 + lane)*8 + e  == W[n][k],
//   n = nt*16 + (lane&15), k = kt*32 + (lane>>4)*8 + e   (MFMA B-frag layout)
__global__ void k_prep_w(const float* __restrict__ Wih, const float* __restrict__ Whh,
                         const float* __restrict__ Who, _Float16* __restrict__ wblob) {
  int wi = blockIdx.x >> 4;
  int kt = blockIdx.x & 15;
  const float* S = (wi < 4) ? (Wih + (size_t)wi*HH*DD)
                 : (wi < 8) ? (Whh + (size_t)(wi-4)*HH*HH)
                            :  Who;
  for (int it = 0; it < 8; ++it) {
    int flat = it*256 + threadIdx.x;          // 0..2047 = nt*64+lane
    int lane = flat & 63;
    int n  = (flat >> 6)*16 + (lane & 15);
    int k0 = kt*32 + (lane >> 4)*8;
    const float* s = S + (size_t)n*512 + k0;
    h8 h;
    #pragma unroll
    for (int e = 0; e < 8; ++e) h[e] = (_Float16)s[e];
    *(h8*)(wblob + (size_t)(wi*16+kt)*16384 + (size_t)flat*8) = h;
  }
}

// ---------------- phase A: zi GEMM + fused LayerNorm -> lni2 ----------------
__launch_bounds__(256,1)
__global__ void k_gemm_lni(const float* __restrict__ x,
                           const _Float16* __restrict__ wblob,
                           const float* __restrict__ b_ih,
                           const float* __restrict__ g_ih,
                           const float* __restrict__ be_ih,
                           _Float16* __restrict__ lni) {
  __shared__ __align__(16) _Float16 Bst[16384];   // 32 KB frag-order W chunk
  __shared__ __align__(16) char     Ast[64*80];   // 64 rows x 32 f16, 80B padded stride
  __shared__ float stats[4][4][16][2];
  int tid = threadIdx.x, lane = tid & 63, w = tid >> 6;
  int ln15 = lane & 15;
  int l   = blockIdx.x >> 10;
  int rb0 = (blockIdx.x & 1023) * 64;

  float breg[8], greg[8], bereg[8];
  #pragma unroll
  for (int i = 0; i < 8; ++i) {
    int j = (w*8+i)*16 + ln15;
    breg[i]  = b_ih [l*512 + j];
    greg[i]  = g_ih [l*512 + j];
    bereg[i] = be_ih[l*512 + j];
  }
  f4 acc[4][8];
  #pragma unroll
  for (int mt = 0; mt < 4; ++mt)
    #pragma unroll
    for (int i = 0; i < 8; ++i) acc[mt][i] = (f4){0.f,0.f,0.f,0.f};

  for (int kt = 0; kt < 16; ++kt) {
    const _Float16* bsrc = wblob + (size_t)(l*16 + kt)*16384;
    #pragma unroll
    for (int it = 0; it < 8; ++it) {
      int off = it*2048 + tid*8;
      *(uint4*)&Bst[off] = *(const uint4*)&bsrc[off];
    }
    { int row = tid >> 2, slot = tid & 3;
      const float* asrc = x + (size_t)(rb0+row)*512 + kt*32 + slot*8;
      float4 fa = *(const float4*)asrc;
      float4 fb = *(const float4*)(asrc + 4);
      h8 hv;
      hv[0]=(_Float16)fa.x; hv[1]=(_Float16)fa.y; hv[2]=(_Float16)fa.z; hv[3]=(_Float16)fa.w;
      hv[4]=(_Float16)fb.x; hv[5]=(_Float16)fb.y; hv[6]=(_Float16)fb.z; hv[7]=(_Float16)fb.w;
      *(h8*)&Ast[row*80 + slot*16] = hv; }
    __syncthreads();
    h8 af[4];
    #pragma unroll
    for (int mt = 0; mt < 4; ++mt)
      af[mt] = *(const h8*)&Ast[(mt*16 + ln15)*80 + (lane>>4)*16];
    #pragma unroll
    for (int i = 0; i < 8; ++i) {
      h8 bf = *(const h8*)&Bst[((w*8+i)*64 + lane)*8];
      #pragma unroll
      for (int mt = 0; mt < 4; ++mt)
        acc[mt][i] = __builtin_amdgcn_mfma_f32_16x16x32_f16(af[mt], bf, acc[mt][i], 0,0,0);
    }
    __syncthreads();
  }
  // epilogue: bias + LN stats (row = rb0 + mt*16 + (lane>>4)*4 + r, col j)
  float ps[4][4], pq[4][4];
  #pragma unroll
  for (int mt = 0; mt < 4; ++mt)
    #pragma unroll
    for (int r = 0; r < 4; ++r) { ps[mt][r] = 0.f; pq[mt][r] = 0.f; }
  #pragma unroll
  for (int mt = 0; mt < 4; ++mt)
    #pragma unroll
    for (int i = 0; i < 8; ++i)
      #pragma unroll
      for (int r = 0; r < 4; ++r) {
        float v = acc[mt][i][r] + breg[i];
        acc[mt][i][r] = v;
        ps[mt][r] += v; pq[mt][r] += v*v;
      }
  #pragma unroll
  for (int m = 1; m < 16; m <<= 1)
    #pragma unroll
    for (int mt = 0; mt < 4; ++mt)
      #pragma unroll
      for (int r = 0; r < 4; ++r) {
        ps[mt][r] += __shfl_xor(ps[mt][r], m);
        pq[mt][r] += __shfl_xor(pq[mt][r], m);
      }
  if (ln15 == 0) {
    int g = lane >> 4;
    #pragma unroll
    for (int mt = 0; mt < 4; ++mt)
      #pragma unroll
      for (int r = 0; r < 4; ++r) {
        stats[w][mt][g*4+r][0] = ps[mt][r];
        stats[w][mt][g*4+r][1] = pq[mt][r];
      }
  }
  __syncthreads();
  #pragma unroll
  for (int mt = 0; mt < 4; ++mt)
    #pragma unroll
    for (int r = 0; r < 4; ++r) {
      int rowm = (lane>>4)*4 + r;
      float s = 0.f, q = 0.f;
      #pragma unroll
      for (int ww = 0; ww < 4; ++ww) { s += stats[ww][mt][rowm][0]; q += stats[ww][mt][rowm][1]; }
      float mu = s * (1.f/512.f);
      float rs = rsqrtf(q*(1.f/512.f) - mu*mu + EPSF);
      int rglob = rb0 + mt*16 + rowm;
      int b = rglob >> 11, t = rglob & 2047;
      int ch = b >> 4, c = b & 15;
      // lane-layout store: [lc][t][np=j>>5][lane2=(c>>2)*16+(j&15)][slot=((j>>4)&1)*4+(c&3)]
      _Float16* dst = lni + ((size_t)(l*2 + ch)*2048 + t)*8192;
      #pragma unroll
      for (int i = 0; i < 8; ++i) {
        int j = (w*8+i)*16 + ln15;
        size_t a2 = ((size_t)(j>>5)*64 + (c>>2)*16 + (j&15))*8 + ((j>>4)&1)*4 + (c&3);
        dst[a2] = (_Float16)((acc[mt][i][r] - mu)*rs*greg[i] + bereg[i]);
      }
    }
}

// ---------------- recurrence: 16 blocks, K-half x chain-half ----------------
// bid: l=bid>>2, ch=(bid>>1)&1 (chains b=ch*16+c), kh=bid&1 (K-half); partner=bid^1
// W_hh[l][all n][own 256 k] pinned in regs via VOLATILE init loads (no remat).
// One tagged relaxed-atomic u64 exchange per step; hang-proof cumulative budget.
__launch_bounds__(512,2)
__global__ void k_rnn(const _Float16* __restrict__ wblob,
                      const _Float16* __restrict__ lni2,
                      const float* __restrict__ b_hh,
                      const float* __restrict__ g_hh,
                      const float* __restrict__ be_hh,
                      _Float16* __restrict__ h3,
                      float* __restrict__ hfin,
                      unsigned long long* __restrict__ pz) {
  __shared__ __align__(16) _Float16 hA[16*256];   // [chain][own-k], XOR-swizzled, 8 KB
  __shared__ float stats[8][16][2];
  __shared__ float bstats[16][2];

  const int tid = threadIdx.x, lane = tid & 63, w = tid >> 6;
  const int bid = blockIdx.x;
  const int l = bid >> 2, ch = (bid >> 1) & 1, kh = bid & 1;
  const int lc = l*2 + ch;
  const int g = lane >> 4, ln15 = lane & 15;
  const bool ownhalf = ((w >> 2) == kh);

  // W_hh own K-half -> registers, via volatile loads (cannot be rematerialized)
  h8 wf[8][4];
  {
    const volatile unsigned long long* wv =
      (const volatile unsigned long long*)wblob;
    #pragma unroll
    for (int q = 0; q < 8; ++q) {
      int ktg = kh*8 + q;
      #pragma unroll
      for (int i = 0; i < 4; ++i) {
        int nt = w*4 + i;
        size_t e16 = ((size_t)((4+l)*16 + ktg)*32 + nt)*512 + (size_t)lane*8;
        union { unsigned long long u[2]; h8 v; } uu;
        uu.u[0] = wv[(e16 >> 2) + 0];
        uu.u[1] = wv[(e16 >> 2) + 1];
        wf[q][i] = uu.v;
      }
    }
  }
  float bh[4], gh[4], beh[4];
  #pragma unroll
  for (int i = 0; i < 4; ++i) {
    int j = (w*4+i)*16 + ln15;
    bh[i] = b_hh[l*512 + j]; gh[i] = g_hh[l*512 + j]; beh[i] = be_hh[l*512 + j];
  }
  // h0 = 0 (8 KB = 512 threads x 16B)
  *(uint4*)((char*)hA + tid*16) = make_uint4(0,0,0,0);

  // LNi[t=0] per-lane prefetch (each lane's 2x16B are exactly its finish data)
  uint4 c0, c1;
  {
    const uint4* s = (const uint4*)(lni2 + (size_t)lc*2048*8192);
    c0 = s[(w*2+0)*64 + lane];
    c1 = s[(w*2+1)*64 + lane];
  }
  unsigned long long* pzbase = pz + (size_t)lc*2*2*4096;  // [parity][kh][q8][tid512]
  int pollbudget = 1 << 22;   // cumulative across all steps: hang-proof
  __syncthreads();

  #pragma unroll 1
  for (int t = 0; t < TT; ++t) {
    // prefetch LNi[t+1]
    uint4 p0 = make_uint4(0,0,0,0), p1 = p0;
    if (t+1 < TT) {
      const uint4* s = (const uint4*)(lni2 + ((size_t)lc*2048 + t + 1)*8192);
      p0 = s[(w*2+0)*64 + lane];
      p1 = s[(w*2+1)*64 + lane];
    }
    // partial z = W_half . h_half   (A rows = chains, cols j = nt*16+ln15)
    f4 acc[4];
    #pragma unroll
    for (int i = 0; i < 4; ++i) acc[i] = (f4){0.f,0.f,0.f,0.f};
    #pragma unroll
    for (int q = 0; q < 8; ++q) {
      int a_off = (ln15*512 + q*64 + g*16) ^ ((ln15 & 7) << 4);  // bytes
      h8 a = *(const h8*)((const char*)hA + a_off);
      #pragma unroll
      for (int i = 0; i < 4; ++i)
        acc[i] = __builtin_amdgcn_mfma_f32_16x16x32_f16(a, wf[q][i], acc[i], 0,0,0);
    }
    const unsigned tg = (unsigned)((t+1) & 3);
    unsigned long long* wp = pzbase + ((size_t)(t & 1)*2 + kh)*4096;
    unsigned long long* rp = pzbase + ((size_t)(t & 1)*2 + (kh ^ 1))*4096;
    // publish own partials: per-f32 tag in 2 mantissa LSBs, packed 2-per-u64,
    // [q][tid] layout -> each wave store = 512B contiguous (coalesced)
    #pragma unroll
    for (int q8 = 0; q8 < 8; ++q8) {
      int i = q8 >> 1, r0 = (q8 & 1)*2;
      unsigned lo = (__float_as_uint(acc[i][r0+0]) & ~3u) | tg;
      unsigned hi = (__float_as_uint(acc[i][r0+1]) & ~3u) | tg;
      unsigned long long u = ((unsigned long long)hi << 32) | lo;
      __hip_atomic_store(wp + q8*512 + tid, u, __ATOMIC_RELAXED, __HIP_MEMORY_SCOPE_AGENT);
    }
    __atomic_signal_fence(__ATOMIC_SEQ_CST);  // compiler: don't sink stores past poll
    // poll partner partials (first pass pipelined, then retry stale words)
    unsigned long long vv[8];
    #pragma unroll
    for (int q8 = 0; q8 < 8; ++q8)
      vv[q8] = __hip_atomic_load(rp + q8*512 + tid, __ATOMIC_RELAXED, __HIP_MEMORY_SCOPE_AGENT);
    while (pollbudget > 0) {
      bool ok = true;
      #pragma unroll
      for (int q8 = 0; q8 < 8; ++q8) {
        if (((unsigned)vv[q8] & 3u) != tg || ((unsigned)(vv[q8] >> 32) & 3u) != tg) {
          ok = false;
          vv[q8] = __hip_atomic_load(rp + q8*512 + tid, __ATOMIC_RELAXED, __HIP_MEMORY_SCOPE_AGENT);
        }
      }
      if (ok) break;
      --pollbudget;
    }
    // full z + bias; LN stats over all 512 j (8 waves x 64 j each)
    float z[4][4];
    float ps[4] = {0,0,0,0}, pq[4] = {0,0,0,0};
    #pragma unroll
    for (int i = 0; i < 4; ++i)
      #pragma unroll
      for (int r = 0; r < 4; ++r) {
        unsigned pw = (r & 1) ? (unsigned)(vv[i*2 + (r>>1)] >> 32)
                              : (unsigned)(vv[i*2 + (r>>1)]);
        float v = acc[i][r] + __uint_as_float(pw) + bh[i];
        z[i][r] = v; ps[r] += v; pq[r] += v*v;
      }
    #pragma unroll
    for (int m = 1; m < 16; m <<= 1)
      #pragma unroll
      for (int r = 0; r < 4; ++r) { ps[r] += __shfl_xor(ps[r], m); pq[r] += __shfl_xor(pq[r], m); }
    if (ln15 == 0)
      #pragma unroll
      for (int r = 0; r < 4; ++r) { stats[w][g*4+r][0] = ps[r]; stats[w][g*4+r][1] = pq[r]; }
    __syncthreads();
    if (tid < 32) {
      int c = tid >> 1, sel = tid & 1;
      float s = 0.f;
      #pragma unroll
      for (int ww = 0; ww < 8; ++ww) s += stats[ww][c][sel];
      bstats[c][sel] = s;
    }
    __syncthreads();
    // finish: LN + LNi + tanh; write own-half h to hA, l3 h3, final h
    #pragma unroll
    for (int r = 0; r < 4; ++r) {
      int c = g*4 + r;
      float mu = bstats[c][0] * (1.f/512.f);
      float rs = rsqrtf(bstats[c][1]*(1.f/512.f) - mu*mu + EPSF);
      #pragma unroll
      for (int i = 0; i < 4; ++i) {
        int j = (w*4+i)*16 + ln15;
        h8 lc0 = *(h8*)&c0, lc1 = *(h8*)&c1;
        float lniv = (float)((i < 2) ? lc0[(i&1)*4 + r] : lc1[(i&1)*4 + r]);
        float pre = (z[i][r] - mu)*rs*gh[i] + beh[i] + lniv;
        float e = __expf(2.f*pre);
        float hv = 1.f - 2.f*__builtin_amdgcn_rcpf(e + 1.f);
        if (ownhalf) {
          int kl = j - kh*256;
          int ha_off = (c*512 + kl*2) ^ ((c & 7) << 4);
          *(_Float16*)((char*)hA + ha_off) = (_Float16)hv;
        }
        if (l == 3 && kh == 0)
          h3[((size_t)(ch*16 + c)*2048 + t)*512 + j] = (_Float16)hv;
        if (t == TT-1 && kh == 0)
          hfin[((size_t)l*32 + ch*16 + c)*512 + j] = hv;
      }
    }
    __syncthreads();
    c0 = p0; c1 = p1;
  }
}

// ---------------- phase C: out = h3*W_ho^T + b_ho + x ----------------
__launch_bounds__(256,1)
__global__ void k_gemm_out(const _Float16* __restrict__ h3,
                           const _Float16* __restrict__ wblob,
                           const float* __restrict__ b_ho,
                           const float* __restrict__ x,
                           float* __restrict__ out) {
  __shared__ __align__(16) _Float16 Bst[16384];
  __shared__ __align__(16) char     Ast[64*80];
  int tid = threadIdx.x, lane = tid & 63, w = tid >> 6;
  int rb0 = blockIdx.x * 64;
  float breg[8];
  #pragma unroll
  for (int i = 0; i < 8; ++i) breg[i] = b_ho[(w*8+i)*16 + (lane & 15)];
  f4 acc[4][8];
  #pragma unroll
  for (int mt = 0; mt < 4; ++mt)
    #pragma unroll
    for (int i = 0; i < 8; ++i) acc[mt][i] = (f4){0.f,0.f,0.f,0.f};
  for (int kt = 0; kt < 16; ++kt) {
    const _Float16* bsrc = wblob + (size_t)(128 + kt)*16384;  // wi=8 (W_ho)
    #pragma unroll
    for (int it = 0; it < 8; ++it) {
      int off = it*2048 + tid*8;
      *(uint4*)&Bst[off] = *(const uint4*)&bsrc[off];
    }
    { int row = tid >> 2, slot = tid & 3;
      const _Float16* asrc = h3 + (size_t)(rb0+row)*512 + kt*32 + slot*8;
      *(uint4*)&Ast[row*80 + slot*16] = *(const uint4*)asrc; }
    __syncthreads();
    h8 af[4];
    #pragma unroll
    for (int mt = 0; mt < 4; ++mt)
      af[mt] = *(const h8*)&Ast[(mt*16 + (lane&15))*80 + (lane>>4)*16];
    #pragma unroll
    for (int i = 0; i < 8; ++i) {
      h8 bf = *(const h8*)&Bst[((w*8+i)*64 + lane)*8];
      #pragma unroll
      for (int mt = 0; mt < 4; ++mt)
        acc[mt][i] = __builtin_amdgcn_mfma_f32_16x16x32_f16(af[mt], bf, acc[mt][i], 0,0,0);
    }
    __syncthreads();
  }
  #pragma unroll
  for (int mt = 0; mt < 4; ++mt)
    #pragma unroll
    for (int r = 0; r < 4; ++r) {
      int rglob = rb0 + mt*16 + (lane>>4)*4 + r;
      #pragma unroll
      for (int i = 0; i < 8; ++i) {
        int j = (w*8+i)*16 + (lane & 15);
        out[(size_t)rglob*512 + j] = acc[mt][i][r] + breg[i] + x[(size_t)rglob*512 + j];
      }
    }
}

extern "C" void kernel_launch(void* const* d_in, const int* in_sizes, int n_in,
                              void* d_out, int out_size, void* d_ws, size_t ws_size,
                              hipStream_t stream) {
  const float* x    = (const float*)d_in[0];
  const float* Wih  = (const float*)d_in[1];
  const float* bih  = (const float*)d_in[2];
  const float* gih  = (const float*)d_in[3];
  const float* beih = (const float*)d_in[4];
  const float* Whh  = (const float*)d_in[5];
  const float* bhh  = (const float*)d_in[6];
  const float* ghh  = (const float*)d_in[7];
  const float* behh = (const float*)d_in[8];
  const float* Who  = (const float*)d_in[9];
  const float* bho  = (const float*)d_in[10];
  if (ws_size < WS_END) return;   // need ~341 MiB scratch
  char* ws = (char*)d_ws;
  _Float16* wblob = (_Float16*)(ws + WS_WBLOB);
  _Float16* lni   = (_Float16*)(ws + WS_LNI);
  _Float16* h3    = (_Float16*)(ws + WS_H3);
  unsigned long long* pz = (unsigned long long*)(ws + WS_PZ);
  float* outp = (float*)d_out;

  hipMemsetAsync(pz, 0, (size_t)8*2*2*8*512*8, stream);  // init tag 0 != first tags 1,2
  k_prep_w  <<<144,  256, 0, stream>>>(Wih, Whh, Who, wblob);
  k_gemm_lni<<<4096, 256, 0, stream>>>(x, wblob, bih, gih, beih, lni);
  k_rnn     <<<16,   512, 0, stream>>>(wblob, lni, bhh, ghh, behh, h3,
                                       outp + (size_t)BT*DD, pz);
  k_gemm_out<<<1024, 256, 0, stream>>>(h3, wblob, bho, x, outp);
}